// Round 7
// baseline (109.431 us; speedup 1.0000x reference)
//
#include <hip/hip_runtime.h>
#include <hip/hip_bf16.h>

#define CC 20480      // columns of X
#define PP 2048       // P
#define NROWS 2047    // rows reduced
#define SRR 10
#define HH 1024
#define NCH 64        // row chunks (32 rows each)

typedef __attribute__((ext_vector_type(8))) short short8;
typedef __attribute__((ext_vector_type(4))) float f32x4;

// ---------------- split helper ----------------------------------------
__device__ __forceinline__ void split_bf16(float v, unsigned short& hi, unsigned short& lo) {
    __hip_bfloat16 h = __float2bfloat16(v);
    float r = v - __bfloat162float(h);
    __hip_bfloat16 l2 = __float2bfloat16(r);
    hi = *(unsigned short*)&h;
    lo = *(unsigned short*)&l2;
}

// ---------------- pre: coalesced colsum (blocks 0..511) + wconv --------
// colsum: block (kb,chunk) produces psum for k in [kb*256, kb*256+256)
// over rows [chunk*32, +32). Instead of a 40B-stride gather, load the
// contiguous row window [10*k0-64, 10*k0+2560) as float4 streams into
// LDS (global_load_lds), then pick elements LDS-side. Same bytes, max-
// efficiency coalescing. Double-buffered across rows.
__global__ __launch_bounds__(256) void pre_k(const float* __restrict__ X,
                                             const int* __restrict__ p,
                                             float* __restrict__ psum,
                                             const float* __restrict__ W2,
                                             unsigned short* __restrict__ w2h,
                                             unsigned short* __restrict__ w2l,
                                             const float* __restrict__ W3,
                                             unsigned short* __restrict__ w3h,
                                             unsigned short* __restrict__ w3l) {
    int b = blockIdx.x, t = threadIdx.x;
    if (b < 512) {
        __shared__ float rowbuf[2][3072];     // 24 KB (span 2624 + junk pad)
        __shared__ int pcache[32];
        int kb = b & 7, chunk = b >> 3;
        int k0 = kb * 256;
        int r0 = chunk * 32;
        int r1 = r0 + 32; if (r1 > NROWS) r1 = NROWS;
        if (t < r1 - r0) pcache[t] = p[r0 + t];
        int s0 = 10 * k0 - 64; if (s0 < 0) s0 += CC;
        int w = t >> 6;

        // per-lane span element index (floats): (q*256 + t)*4, q=0..2
        int c0 = s0 + t * 4;              if (c0 >= CC) c0 -= CC;
        int c1 = s0 + (256 + t) * 4;      if (c1 >= CC) c1 -= CC;
        int c2 = s0 + (512 + t) * 4;      if (c2 >= CC) c2 -= CC;

#define STAGEROW(buf, i)                                                          \
    do {                                                                          \
        const float* rp = X + (size_t)(i) * (size_t)(SRR * CC);                   \
        __builtin_amdgcn_global_load_lds(                                          \
            (const __attribute__((address_space(1))) void*)(rp + c0),             \
            (__attribute__((address_space(3))) void*)&rowbuf[buf][w * 256], 16, 0, 0); \
        __builtin_amdgcn_global_load_lds(                                          \
            (const __attribute__((address_space(1))) void*)(rp + c1),             \
            (__attribute__((address_space(3))) void*)&rowbuf[buf][1024 + w * 256], 16, 0, 0); \
        __builtin_amdgcn_global_load_lds(                                          \
            (const __attribute__((address_space(1))) void*)(rp + c2),             \
            (__attribute__((address_space(3))) void*)&rowbuf[buf][2048 + w * 256], 16, 0, 0); \
    } while (0)

        STAGEROW(0, r0);
        __syncthreads();                  // pcache ready + row r0 landed
        float s = 0.f;
        int ebase = 10 * t + 64;
        for (int i = r0; i < r1; ++i) {
            int cur = (i - r0) & 1;
            if (i + 1 < r1) STAGEROW(cur ^ 1, i + 1);
            s += rowbuf[cur][ebase - pcache[i - r0]];
            __syncthreads();              // reads of cur done; next buf landed
        }
#undef STAGEROW
        psum[chunk * PP + k0 + t] = s;
        return;
    }
    int bb = b - 512;
    const float* src; unsigned short *dh, *dl;
    if (bb < 256) { src = W2; dh = w2h; dl = w2l; }
    else { src = W3; dh = w3h; dl = w3l; bb -= 256; }
    int idx = bb * 4096 + t * 16;
    #pragma unroll
    for (int q = 0; q < 4; ++q) {
        float4 v = *(const float4*)&src[idx + q * 4];
        float vv[4] = {v.x, v.y, v.z, v.w};
        ushort hi4[4], lo4[4];
        #pragma unroll
        for (int i = 0; i < 4; ++i) split_bf16(vv[i], hi4[i], lo4[i]);
        *(ushort4*)&dh[idx + q * 4] = *(ushort4*)hi4;
        *(ushort4*)&dl[idx + q * 4] = *(ushort4*)lo4;
    }
}

// ---------------- prep2: x (psum reduce) + layer1, 256 blocks ----------
__global__ __launch_bounds__(256) void prep2_k(const float* __restrict__ psum,
                                               const float* __restrict__ W1,
                                               const float* __restrict__ b1,
                                               unsigned short* __restrict__ h1h,
                                               unsigned short* __restrict__ h1l) {
    __shared__ float xv[8];
    int b = blockIdx.x, t = threadIdx.x;
    int kl = t >> 5;                  // 0..7
    int c = t & 31;
    int k = b * 8 + kl;
    float s = psum[c * PP + k] + psum[(c + 32) * PP + k];
    #pragma unroll
    for (int m2 = 1; m2 < 32; m2 <<= 1) s += __shfl_xor(s, m2, 64);
    if (c == 0) xv[kl] = s * (1.0f / (float)NROWS);
    __syncthreads();
    int o0 = (t & 63) * 16;
    float w[16], bb2[16];
    #pragma unroll
    for (int q = 0; q < 4; ++q) {
        float4 wv = *(const float4*)&W1[o0 + q * 4];
        float4 bv = *(const float4*)&b1[o0 + q * 4];
        w[q*4+0] = wv.x; w[q*4+1] = wv.y; w[q*4+2] = wv.z; w[q*4+3] = wv.w;
        bb2[q*4+0] = bv.x; bb2[q*4+1] = bv.y; bb2[q*4+2] = bv.z; bb2[q*4+3] = bv.w;
    }
    #pragma unroll
    for (int pass = 0; pass < 2; ++pass) {
        int r = (t >> 6) + 4 * pass;          // 0..7
        float x = xv[r];
        ushort hi16[16], lo16[16];
        #pragma unroll
        for (int i = 0; i < 16; ++i) {
            float v = x * w[i] + bb2[i];
            v = v > 0.f ? v : 0.f;
            split_bf16(v, hi16[i], lo16[i]);
        }
        size_t base = (size_t)(b * 8 + r) * HH + o0;
        *(short8*)&h1h[base] = *(short8*)hi16;
        *(short8*)&h1h[base + 8] = *(short8*)&hi16[8];
        *(short8*)&h1l[base] = *(short8*)lo16;
        *(short8*)&h1l[base + 8] = *(short8*)&lo16[8];
    }
}

// ---------------- async global->LDS, 16B/lane -------------------------
__device__ __forceinline__ void gload16(const unsigned short* g, unsigned short* lds) {
    __builtin_amdgcn_global_load_lds(
        (const __attribute__((address_space(1))) void*)g,
        (__attribute__((address_space(3))) void*)lds,
        16, 0, 0);
}

// ---------------- bf16x3 MFMA GEMM, 128x64 tile, 8 waves ---------------
#define BM 128
#define BN 64
#define BK 32
#define NBY 16        // N / BN
#define BUFE 12288    // ushorts per buffer (24 KB)

template<int OUT>
__global__ __launch_bounds__(512, 2) void gemm3x_k(
    const unsigned short* __restrict__ Ah, const unsigned short* __restrict__ Al,
    const unsigned short* __restrict__ Bh, const unsigned short* __restrict__ Bl,
    const float* __restrict__ bias,
    unsigned short* __restrict__ Ch, unsigned short* __restrict__ Cl,
    const float* __restrict__ W4, float* __restrict__ partial,
    int M, int N, int K)
{
    __shared__ unsigned short lds[2][BUFE];   // 48 KB
    int lin = blockIdx.x;
    int v = (lin & 7) * (gridDim.x >> 3) + (lin >> 3);   // XCD-chunked, bijective
    int bx = v >> 4, by = v & (NBY - 1);                 // N-tile fastest
    int bm = bx * BM, bn = by * BN;
    int t = threadIdx.x, w = t >> 6, l = t & 63;
    int lr = l & 15, lk = l >> 4;
    int wr = w >> 1, wc = w & 1;

    size_t offA = (size_t)(bm + w * 16 + lr) * K + lk * 8;
    size_t offB = (size_t)(bn + (w & 3) * 16 + lr) * K + lk * 8;

#define STAGE(buf, k0)                                                   \
    do {                                                                 \
        unsigned short* L = lds[buf];                                    \
        gload16(Ah + offA + (k0), L + w * 512);                          \
        gload16(Al + offA + (k0), L + 4096 + w * 512);                   \
        if (w < 4) gload16(Bh + offB + (k0), L + 8192 + w * 512);        \
        else       gload16(Bl + offB + (k0), L + 10240 + (w - 4) * 512); \
    } while (0)

    f32x4 acc[2][2];
    #pragma unroll
    for (int i = 0; i < 2; ++i)
        #pragma unroll
        for (int j = 0; j < 2; ++j) acc[i][j] = (f32x4)(0.f);

    STAGE(0, 0);
    __syncthreads();

    int nt = K / BK;                       // 32 steps
    for (int tt = 0; tt < nt; ++tt) {
        int cur = tt & 1;
        if (tt + 1 < nt) STAGE(cur ^ 1, (tt + 1) * BK);
        unsigned short* L = lds[cur];
        short8 ah2[2], al2[2], bh2[2], bl2[2];
        #pragma unroll
        for (int mi = 0; mi < 2; ++mi) {
            ah2[mi] = *(const short8*)&L[(wr * 2 + mi) * 512 + l * 8];
            al2[mi] = *(const short8*)&L[4096 + (wr * 2 + mi) * 512 + l * 8];
        }
        #pragma unroll
        for (int ni = 0; ni < 2; ++ni) {
            bh2[ni] = *(const short8*)&L[8192 + (wc * 2 + ni) * 512 + l * 8];
            bl2[ni] = *(const short8*)&L[10240 + (wc * 2 + ni) * 512 + l * 8];
        }
        #pragma unroll
        for (int mi = 0; mi < 2; ++mi)
            #pragma unroll
            for (int ni = 0; ni < 2; ++ni) {
                acc[mi][ni] = __builtin_amdgcn_mfma_f32_16x16x32_bf16(ah2[mi], bh2[ni], acc[mi][ni], 0, 0, 0);
                acc[mi][ni] = __builtin_amdgcn_mfma_f32_16x16x32_bf16(ah2[mi], bl2[ni], acc[mi][ni], 0, 0, 0);
                acc[mi][ni] = __builtin_amdgcn_mfma_f32_16x16x32_bf16(al2[mi], bh2[ni], acc[mi][ni], 0, 0, 0);
            }
        __syncthreads();
    }
#undef STAGE

    float bv[2];
    #pragma unroll
    for (int ni = 0; ni < 2; ++ni) bv[ni] = bias[bn + wc * 32 + ni * 16 + lr];
    if (OUT == 1) {
        #pragma unroll
        for (int mi = 0; mi < 2; ++mi)
            #pragma unroll
            for (int ni = 0; ni < 2; ++ni)
                #pragma unroll
                for (int r = 0; r < 4; ++r) {
                    int row = bm + wr * 32 + mi * 16 + lk * 4 + r;
                    int col = bn + wc * 32 + ni * 16 + lr;
                    float vv = acc[mi][ni][r] + bv[ni];
                    vv = vv > 0.f ? vv : 0.f;
                    unsigned short hi, lo;
                    split_bf16(vv, hi, lo);
                    Ch[(size_t)row * N + col] = hi;
                    Cl[(size_t)row * N + col] = lo;
                }
    } else {
        float w4v[2];
        #pragma unroll
        for (int ni = 0; ni < 2; ++ni) w4v[ni] = W4[bn + wc * 32 + ni * 16 + lr];
        #pragma unroll
        for (int mi = 0; mi < 2; ++mi) {
            float ps[4];
            #pragma unroll
            for (int r = 0; r < 4; ++r) {
                float acc_d = 0.f;
                #pragma unroll
                for (int ni = 0; ni < 2; ++ni) {
                    float vv = acc[mi][ni][r] + bv[ni];
                    vv = vv > 0.f ? vv : 0.f;
                    acc_d += vv * w4v[ni];
                }
                ps[r] = acc_d;
            }
            #pragma unroll
            for (int r = 0; r < 4; ++r) {
                #pragma unroll
                for (int m2 = 1; m2 < 16; m2 <<= 1) ps[r] += __shfl_xor(ps[r], m2, 64);
            }
            if (lr == 0) {
                #pragma unroll
                for (int r = 0; r < 4; ++r) {
                    int row = bm + wr * 32 + mi * 16 + lk * 4 + r;
                    partial[(size_t)row * 32 + by * 2 + wc] = ps[r];
                }
            }
        }
    }
}

// ---------------- ysum: y[r] = sum(partial[r][:]) + b4 ----------------
__global__ __launch_bounds__(256) void ysum_k(const float* __restrict__ partial,
                                              const float* __restrict__ b4,
                                              float* __restrict__ y) {
    int r = blockIdx.x * 256 + threadIdx.x;
    float s = 0.f;
    #pragma unroll
    for (int q = 0; q < 8; ++q) {
        float4 v = *(const float4*)&partial[(size_t)r * 32 + q * 4];
        s += v.x + v.y + v.z + v.w;
    }
    y[r] = s + b4[0];
}

extern "C" void kernel_launch(void* const* d_in, const int* in_sizes, int n_in,
                              void* d_out, int out_size, void* d_ws, size_t ws_size,
                              hipStream_t stream) {
    const float* X  = (const float*)d_in[0];
    const int*   p  = (const int*)d_in[1];
    const float* W1 = (const float*)d_in[2];
    const float* b1 = (const float*)d_in[3];
    const float* W2 = (const float*)d_in[4];
    const float* b2 = (const float*)d_in[5];
    const float* W3 = (const float*)d_in[6];
    const float* b3 = (const float*)d_in[7];
    const float* W4 = (const float*)d_in[8];
    const float* b4 = (const float*)d_in[9];
    float* out = (float*)d_out;

    char* ws = (char*)d_ws;
    size_t off = 0;
    float* psum = (float*)(ws + off); off += (size_t)NCH * PP * 4;
    unsigned short* h1h = (unsigned short*)(ws + off); off += (size_t)PP * HH * 2;
    unsigned short* h1l = (unsigned short*)(ws + off); off += (size_t)PP * HH * 2;
    unsigned short* h2h = (unsigned short*)(ws + off); off += (size_t)PP * HH * 2;
    unsigned short* h2l = (unsigned short*)(ws + off); off += (size_t)PP * HH * 2;
    unsigned short* w2h = (unsigned short*)(ws + off); off += (size_t)HH * HH * 2;
    unsigned short* w2l = (unsigned short*)(ws + off); off += (size_t)HH * HH * 2;
    unsigned short* w3h = (unsigned short*)(ws + off); off += (size_t)HH * HH * 2;
    unsigned short* w3l = (unsigned short*)(ws + off); off += (size_t)HH * HH * 2;
    float* partial = (float*)(ws + off); off += (size_t)PP * 32 * 4;

    pre_k<<<1024, 256, 0, stream>>>(X, p, psum, W2, w2h, w2l, W3, w3h, w3l);
    prep2_k<<<256, 256, 0, stream>>>(psum, W1, b1, h1h, h1l);
    gemm3x_k<1><<<(PP / BM) * (HH / BN), 512, 0, stream>>>(
        h1h, h1l, w2h, w2l, b2, h2h, h2l, (const float*)nullptr, (float*)nullptr, PP, HH, HH);
    gemm3x_k<2><<<(PP / BM) * (HH / BN), 512, 0, stream>>>(
        h2h, h2l, w3h, w3l, b3, (unsigned short*)nullptr, (unsigned short*)nullptr, W4, partial, PP, HH, HH);
    ysum_k<<<PP / 256, 256, 0, stream>>>(partial, b4, out);
}

// Round 8
// 88.947 us; speedup vs baseline: 1.2303x; 1.2303x over previous
//
#include <hip/hip_runtime.h>
#include <hip/hip_bf16.h>

#define CC 20480      // columns of X
#define PP 2048       // P
#define NROWS 2047    // rows reduced
#define SRR 10
#define HH 1024
#define NCH 64        // row chunks (32 rows each)

typedef __attribute__((ext_vector_type(8))) short short8;
typedef __attribute__((ext_vector_type(4))) float f32x4;

// ---------------- split helper ----------------------------------------
__device__ __forceinline__ void split_bf16(float v, unsigned short& hi, unsigned short& lo) {
    __hip_bfloat16 h = __float2bfloat16(v);
    float r = v - __bfloat162float(h);
    __hip_bfloat16 l2 = __float2bfloat16(r);
    hi = *(unsigned short*)&h;
    lo = *(unsigned short*)&l2;
}

// ---------------- pre: colsum gather (blocks 0..511) + wconv -----------
__global__ __launch_bounds__(256) void pre_k(const float* __restrict__ X,
                                             const int* __restrict__ p,
                                             float* __restrict__ psum,
                                             const float* __restrict__ W2,
                                             unsigned short* __restrict__ w2h,
                                             unsigned short* __restrict__ w2l,
                                             const float* __restrict__ W3,
                                             unsigned short* __restrict__ w3h,
                                             unsigned short* __restrict__ w3l) {
    int b = blockIdx.x, t = threadIdx.x;
    if (b < 512) {
        int k = (b & 7) * 256 + t;              // 0..2047
        int chunk = b >> 3;                     // 0..63
        int r0 = chunk * 32;
        int r1 = r0 + 32; if (r1 > NROWS) r1 = NROWS;
        float s = 0.f;
        int base = SRR * k;
        for (int i = r0; i < r1; ++i) {
            int col = base - p[i]; if (col < 0) col += CC;   // p[i] in [0,64)
            s += X[(size_t)i * (size_t)(SRR * CC) + col];
        }
        psum[chunk * PP + k] = s;
        return;
    }
    int bb = b - 512;
    const float* src; unsigned short *dh, *dl;
    if (bb < 256) { src = W2; dh = w2h; dl = w2l; }
    else { src = W3; dh = w3h; dl = w3l; bb -= 256; }
    int idx = bb * 4096 + t * 16;
    #pragma unroll
    for (int q = 0; q < 4; ++q) {
        float4 v = *(const float4*)&src[idx + q * 4];
        float vv[4] = {v.x, v.y, v.z, v.w};
        ushort hi4[4], lo4[4];
        #pragma unroll
        for (int i = 0; i < 4; ++i) split_bf16(vv[i], hi4[i], lo4[i]);
        *(ushort4*)&dh[idx + q * 4] = *(ushort4*)hi4;
        *(ushort4*)&dl[idx + q * 4] = *(ushort4*)lo4;
    }
}

// ---------------- prep2: x (psum reduce) + layer1, 256 blocks ----------
__global__ __launch_bounds__(256) void prep2_k(const float* __restrict__ psum,
                                               const float* __restrict__ W1,
                                               const float* __restrict__ b1,
                                               unsigned short* __restrict__ h1h,
                                               unsigned short* __restrict__ h1l) {
    __shared__ float xv[8];
    int b = blockIdx.x, t = threadIdx.x;
    int kl = t >> 5;                  // 0..7
    int c = t & 31;
    int k = b * 8 + kl;
    float s = psum[c * PP + k] + psum[(c + 32) * PP + k];
    #pragma unroll
    for (int m2 = 1; m2 < 32; m2 <<= 1) s += __shfl_xor(s, m2, 64);
    if (c == 0) xv[kl] = s * (1.0f / (float)NROWS);
    __syncthreads();
    int o0 = (t & 63) * 16;
    float w[16], bb2[16];
    #pragma unroll
    for (int q = 0; q < 4; ++q) {
        float4 wv = *(const float4*)&W1[o0 + q * 4];
        float4 bv = *(const float4*)&b1[o0 + q * 4];
        w[q*4+0] = wv.x; w[q*4+1] = wv.y; w[q*4+2] = wv.z; w[q*4+3] = wv.w;
        bb2[q*4+0] = bv.x; bb2[q*4+1] = bv.y; bb2[q*4+2] = bv.z; bb2[q*4+3] = bv.w;
    }
    #pragma unroll
    for (int pass = 0; pass < 2; ++pass) {
        int r = (t >> 6) + 4 * pass;          // 0..7
        float x = xv[r];
        ushort hi16[16], lo16[16];
        #pragma unroll
        for (int i = 0; i < 16; ++i) {
            float v = x * w[i] + bb2[i];
            v = v > 0.f ? v : 0.f;
            split_bf16(v, hi16[i], lo16[i]);
        }
        size_t base = (size_t)(b * 8 + r) * HH + o0;
        *(short8*)&h1h[base] = *(short8*)hi16;
        *(short8*)&h1h[base + 8] = *(short8*)&hi16[8];
        *(short8*)&h1l[base] = *(short8*)lo16;
        *(short8*)&h1l[base + 8] = *(short8*)&lo16[8];
    }
}

// ---------------- async global->LDS, 16B/lane -------------------------
__device__ __forceinline__ void gload16(const unsigned short* g, unsigned short* lds) {
    __builtin_amdgcn_global_load_lds(
        (const __attribute__((address_space(1))) void*)g,
        (__attribute__((address_space(3))) void*)lds,
        16, 0, 0);
}

// ---------------- bf16x3 MFMA GEMM, counted-vmcnt pipeline (T4) --------
// C = relu(A @ B^T + bias). BM=128 BN=64 BK=32, 8 waves, grid 256 =
// 1 block/CU. Per K-step: STAGE(next) [3 gload/wave] -> vmcnt(3) ->
// s_barrier -> 8x ds_read_b128 -> lgkmcnt(0)+sched_barrier -> 12 MFMA
// (setprio-wrapped) -> s_barrier. Loads stay in flight across barriers;
// only the final step drains to vmcnt(0).
#define BM 128
#define BN 64
#define BK 32
#define NBY 16        // N / BN
#define BUFE 12288    // ushorts per buffer (24 KB)

template<int OUT>
__global__ __launch_bounds__(512, 2) void gemm3x_k(
    const unsigned short* __restrict__ Ah, const unsigned short* __restrict__ Al,
    const unsigned short* __restrict__ Bh, const unsigned short* __restrict__ Bl,
    const float* __restrict__ bias,
    unsigned short* __restrict__ Ch, unsigned short* __restrict__ Cl,
    const float* __restrict__ W4, float* __restrict__ partial,
    int M, int N, int K)
{
    __shared__ unsigned short lds[2][BUFE];   // 48 KB
    int lin = blockIdx.x;
    int v = (lin & 7) * (gridDim.x >> 3) + (lin >> 3);   // XCD-chunked, bijective
    int bx = v >> 4, by = v & (NBY - 1);                 // N-tile fastest
    int bm = bx * BM, bn = by * BN;
    int t = threadIdx.x, w = t >> 6, l = t & 63;
    int lr = l & 15, lk = l >> 4;
    int wr = w >> 1, wc = w & 1;

    size_t offA = (size_t)(bm + w * 16 + lr) * K + lk * 8;
    size_t offB = (size_t)(bn + (w & 3) * 16 + lr) * K + lk * 8;

#define STAGE(buf, k0)                                                   \
    do {                                                                 \
        unsigned short* L = lds[buf];                                    \
        gload16(Ah + offA + (k0), L + w * 512);                          \
        gload16(Al + offA + (k0), L + 4096 + w * 512);                   \
        if (w < 4) gload16(Bh + offB + (k0), L + 8192 + w * 512);        \
        else       gload16(Bl + offB + (k0), L + 10240 + (w - 4) * 512); \
    } while (0)

    f32x4 acc[2][2];
    #pragma unroll
    for (int i = 0; i < 2; ++i)
        #pragma unroll
        for (int j = 0; j < 2; ++j) acc[i][j] = (f32x4)(0.f);

    STAGE(0, 0);

    int nt = K / BK;                       // 32 steps
    for (int tt = 0; tt < nt; ++tt) {
        int cur = tt & 1;
        if (tt + 1 < nt) {
            STAGE(cur ^ 1, (tt + 1) * BK);                 // 3 new loads/wave
            asm volatile("s_waitcnt vmcnt(3)" ::: "memory"); // cur's landed
        } else {
            asm volatile("s_waitcnt vmcnt(0)" ::: "memory");
        }
        __builtin_amdgcn_s_barrier();      // all waves' cur-loads landed
        __builtin_amdgcn_sched_barrier(0);
        unsigned short* L = lds[cur];
        short8 ah2[2], al2[2], bh2[2], bl2[2];
        #pragma unroll
        for (int mi = 0; mi < 2; ++mi) {
            ah2[mi] = *(const short8*)&L[(wr * 2 + mi) * 512 + l * 8];
            al2[mi] = *(const short8*)&L[4096 + (wr * 2 + mi) * 512 + l * 8];
        }
        #pragma unroll
        for (int ni = 0; ni < 2; ++ni) {
            bh2[ni] = *(const short8*)&L[8192 + (wc * 2 + ni) * 512 + l * 8];
            bl2[ni] = *(const short8*)&L[10240 + (wc * 2 + ni) * 512 + l * 8];
        }
        asm volatile("s_waitcnt lgkmcnt(0)" ::: "memory");
        __builtin_amdgcn_sched_barrier(0);                 // rule 18
        __builtin_amdgcn_s_setprio(1);
        #pragma unroll
        for (int mi = 0; mi < 2; ++mi)
            #pragma unroll
            for (int ni = 0; ni < 2; ++ni) {
                acc[mi][ni] = __builtin_amdgcn_mfma_f32_16x16x32_bf16(ah2[mi], bh2[ni], acc[mi][ni], 0, 0, 0);
                acc[mi][ni] = __builtin_amdgcn_mfma_f32_16x16x32_bf16(ah2[mi], bl2[ni], acc[mi][ni], 0, 0, 0);
                acc[mi][ni] = __builtin_amdgcn_mfma_f32_16x16x32_bf16(al2[mi], bh2[ni], acc[mi][ni], 0, 0, 0);
            }
        __builtin_amdgcn_s_setprio(0);
        __builtin_amdgcn_s_barrier();      // reads of cur done -> safe to overwrite
        __builtin_amdgcn_sched_barrier(0);
    }
#undef STAGE

    float bv[2];
    #pragma unroll
    for (int ni = 0; ni < 2; ++ni) bv[ni] = bias[bn + wc * 32 + ni * 16 + lr];
    if (OUT == 1) {
        #pragma unroll
        for (int mi = 0; mi < 2; ++mi)
            #pragma unroll
            for (int ni = 0; ni < 2; ++ni)
                #pragma unroll
                for (int r = 0; r < 4; ++r) {
                    int row = bm + wr * 32 + mi * 16 + lk * 4 + r;
                    int col = bn + wc * 32 + ni * 16 + lr;
                    float vv = acc[mi][ni][r] + bv[ni];
                    vv = vv > 0.f ? vv : 0.f;
                    unsigned short hi, lo;
                    split_bf16(vv, hi, lo);
                    Ch[(size_t)row * N + col] = hi;
                    Cl[(size_t)row * N + col] = lo;
                }
    } else {
        float w4v[2];
        #pragma unroll
        for (int ni = 0; ni < 2; ++ni) w4v[ni] = W4[bn + wc * 32 + ni * 16 + lr];
        #pragma unroll
        for (int mi = 0; mi < 2; ++mi) {
            float ps[4];
            #pragma unroll
            for (int r = 0; r < 4; ++r) {
                float acc_d = 0.f;
                #pragma unroll
                for (int ni = 0; ni < 2; ++ni) {
                    float vv = acc[mi][ni][r] + bv[ni];
                    vv = vv > 0.f ? vv : 0.f;
                    acc_d += vv * w4v[ni];
                }
                ps[r] = acc_d;
            }
            #pragma unroll
            for (int r = 0; r < 4; ++r) {
                #pragma unroll
                for (int m2 = 1; m2 < 16; m2 <<= 1) ps[r] += __shfl_xor(ps[r], m2, 64);
            }
            if (lr == 0) {
                #pragma unroll
                for (int r = 0; r < 4; ++r) {
                    int row = bm + wr * 32 + mi * 16 + lk * 4 + r;
                    partial[(size_t)row * 32 + by * 2 + wc] = ps[r];
                }
            }
        }
    }
}

// ---------------- ysum: y[r] = sum(partial[r][:]) + b4 ----------------
__global__ __launch_bounds__(256) void ysum_k(const float* __restrict__ partial,
                                              const float* __restrict__ b4,
                                              float* __restrict__ y) {
    int r = blockIdx.x * 256 + threadIdx.x;
    float s = 0.f;
    #pragma unroll
    for (int q = 0; q < 8; ++q) {
        float4 v = *(const float4*)&partial[(size_t)r * 32 + q * 4];
        s += v.x + v.y + v.z + v.w;
    }
    y[r] = s + b4[0];
}

extern "C" void kernel_launch(void* const* d_in, const int* in_sizes, int n_in,
                              void* d_out, int out_size, void* d_ws, size_t ws_size,
                              hipStream_t stream) {
    const float* X  = (const float*)d_in[0];
    const int*   p  = (const int*)d_in[1];
    const float* W1 = (const float*)d_in[2];
    const float* b1 = (const float*)d_in[3];
    const float* W2 = (const float*)d_in[4];
    const float* b2 = (const float*)d_in[5];
    const float* W3 = (const float*)d_in[6];
    const float* b3 = (const float*)d_in[7];
    const float* W4 = (const float*)d_in[8];
    const float* b4 = (const float*)d_in[9];
    float* out = (float*)d_out;

    char* ws = (char*)d_ws;
    size_t off = 0;
    float* psum = (float*)(ws + off); off += (size_t)NCH * PP * 4;
    unsigned short* h1h = (unsigned short*)(ws + off); off += (size_t)PP * HH * 2;
    unsigned short* h1l = (unsigned short*)(ws + off); off += (size_t)PP * HH * 2;
    unsigned short* h2h = (unsigned short*)(ws + off); off += (size_t)PP * HH * 2;
    unsigned short* h2l = (unsigned short*)(ws + off); off += (size_t)PP * HH * 2;
    unsigned short* w2h = (unsigned short*)(ws + off); off += (size_t)HH * HH * 2;
    unsigned short* w2l = (unsigned short*)(ws + off); off += (size_t)HH * HH * 2;
    unsigned short* w3h = (unsigned short*)(ws + off); off += (size_t)HH * HH * 2;
    unsigned short* w3l = (unsigned short*)(ws + off); off += (size_t)HH * HH * 2;
    float* partial = (float*)(ws + off); off += (size_t)PP * 32 * 4;

    pre_k<<<1024, 256, 0, stream>>>(X, p, psum, W2, w2h, w2l, W3, w3h, w3l);
    prep2_k<<<256, 256, 0, stream>>>(psum, W1, b1, h1h, h1l);
    gemm3x_k<1><<<(PP / BM) * (HH / BN), 512, 0, stream>>>(
        h1h, h1l, w2h, w2l, b2, h2h, h2l, (const float*)nullptr, (float*)nullptr, PP, HH, HH);
    gemm3x_k<2><<<(PP / BM) * (HH / BN), 512, 0, stream>>>(
        h2h, h2l, w3h, w3l, b3, (unsigned short*)nullptr, (unsigned short*)nullptr, W4, partial, PP, HH, HH);
    ysum_k<<<PP / 256, 256, 0, stream>>>(partial, b4, out);
}